// Round 19
// baseline (255.840 us; speedup 1.0000x reference)
//
#include <hip/hip_runtime.h>
#include <stdint.h>

typedef __attribute__((ext_vector_type(8))) short short8;
typedef __attribute__((ext_vector_type(4))) short short4v;
typedef __attribute__((ext_vector_type(4))) float f32x4;
typedef __attribute__((ext_vector_type(2))) unsigned int uint2v;

#define B_ 4
#define T_ 2048
#define C_ 1024
#define H_ 16
#define D_ 64
#define C3_ 3072

#define AS1 __attribute__((address_space(1)))
#define AS3 __attribute__((address_space(3)))

#define QK_SCALE 0.18033688f   /* 1/sqrt(64) * log2(e), folded into Q at GEMM1 epilogue */

__device__ __forceinline__ unsigned short f2bf(float f) {
    union { float f; uint32_t u; } v; v.f = f;
    uint32_t r = v.u + 0x7FFFu + ((v.u >> 16) & 1u);
    return (unsigned short)(r >> 16);
}

__device__ __forceinline__ uint32_t pk_bf16(float lo, float hi) {
    uint32_t r;
    asm("v_cvt_pk_bf16_f32 %0, %1, %2" : "=v"(r) : "v"(lo), "v"(hi));
    return r;
}

// ---------------- W[K][N] fp32 -> WT[N][K] bf16 (device helper) ----------------
__device__ __forceinline__ void wtrans_body(const float* __restrict__ W, unsigned short* __restrict__ WT,
                                            int K, int N, int n0, int k0, int tx, int ty,
                                            float (*t)[33]) {
#pragma unroll
    for (int i = 0; i < 4; ++i)
        t[ty + i * 8][tx] = W[(size_t)(k0 + ty + i * 8) * N + n0 + tx];
    __syncthreads();
#pragma unroll
    for (int i = 0; i < 4; ++i)
        WT[(size_t)(n0 + ty + i * 8) * K + k0 + tx] = f2bf(t[tx][ty + i * 8]);
}

// ---------------- fused prologue: x->bf16 + both weight transposes ----------------
// blocks [0,8192): cvt;  [8192,11264): Wa trans (96x32);  [11264,12288): Wp trans (32x32)
__global__ __launch_bounds__(256) void k_prep(const float* __restrict__ x, unsigned short* __restrict__ xb,
                                              const float* __restrict__ Wa, unsigned short* __restrict__ wat,
                                              const float* __restrict__ Wp, unsigned short* __restrict__ wpt) {
    __shared__ float t[32][33];
    int bid = blockIdx.x;
    int tid = threadIdx.x;
    if (bid < 8192) {
        int i = bid * 256 + tid;
        float4 v = ((const float4*)x)[i];
        unsigned short o0 = f2bf(v.x), o1 = f2bf(v.y), o2 = f2bf(v.z), o3 = f2bf(v.w);
        unsigned long long packed = (unsigned long long)o0 | ((unsigned long long)o1 << 16)
            | ((unsigned long long)o2 << 32) | ((unsigned long long)o3 << 48);
        *(unsigned long long*)(xb + (size_t)i * 4) = packed;
    } else if (bid < 11264) {
        int lb = bid - 8192;
        wtrans_body(Wa, wat, C_, C3_, (lb % 96) * 32, (lb / 96) * 32, tid & 31, tid >> 5, t);
    } else {
        int lb = bid - 11264;
        wtrans_body(Wp, wpt, C_, C_, (lb % 32) * 32, (lb / 32) * 32, tid & 31, tid >> 5, t);
    }
}

// ---------------- extract V head-major transposed: vt[bh][d][t] ----------------
__global__ void k_prep_vt(const unsigned short* __restrict__ qkv, unsigned short* __restrict__ vt) {
    int bh = blockIdx.y; int b = bh >> 4, h = bh & 15;
    int t0 = blockIdx.x * 64;
    __shared__ unsigned short tile[64][72];
    int tid = threadIdx.x;
    int r = tid >> 3;          // 0..31
    int c = (tid & 7) * 8;     // 0..56
#pragma unroll
    for (int rr = 0; rr < 64; rr += 32) {
        const unsigned short* src = qkv + (size_t)(b * T_ + t0 + r + rr) * C3_ + 2 * C_ + h * D_ + c;
        short8 v = *(const short8*)src;
#pragma unroll
        for (int j = 0; j < 8; ++j) tile[r + rr][c + j] = (unsigned short)v[j];
    }
    __syncthreads();
#pragma unroll
    for (int rr = 0; rr < 64; rr += 32) {
        int d = r + rr;
        short8 sv;
#pragma unroll
        for (int j = 0; j < 8; ++j) sv[j] = (short)tile[c + j][d];
        *(short8*)(vt + (size_t)bh * D_ * T_ + (size_t)d * T_ + t0 + c) = sv;
    }
}

// ---------------- GEMM (BM=256): C[M][N] = A @ BT^T + bias ----------------
// BM=256, BN=128, BK=32, 256 threads (4 waves: 2M x 2N), per-wave output 128x64.
// 2-buffer classic double-buffer (24KB/buf = 48KB -> 3 blocks/CU; grid 768 = all co-resident,
// zero scheduling tail), vmcnt(0)+barrier per tile (drain hidden by 3-block TLP).
// Swizzle slot ^= ((row>>1)&3) via pre-swizzled global source (0 conflicts, r10-verified).
template<bool OUT_BF16>
__global__ __launch_bounds__(256, 3) void k_gemm_bt(const unsigned short* __restrict__ A,
                                                    const unsigned short* __restrict__ BT,
                                                    const float* __restrict__ bias,
                                                    unsigned short* __restrict__ outb,
                                                    float* __restrict__ outf,
                                                    int M, int N, int K) {
    __shared__ __align__(16) char arena[49152];
    int tid = threadIdx.x;
    int w = tid >> 6, lane = tid & 63;
    int wrow = w >> 1, wcol = w & 1;

    int lin = blockIdx.y * gridDim.x + blockIdx.x;
    int nwg8 = (gridDim.x * gridDim.y) >> 3;
    int newlin = (lin & 7) * nwg8 + (lin >> 3);
    int bx = newlin % gridDim.x;
    int by = newlin / gridDim.x;
    int m0 = by * 256, n0 = bx * 128;

    int lr = lane & 15, lg = lane >> 4;

    f32x4 acc[8][4] = {};

    int scb = ((tid & 3) << 4) ^ (((tid >> 3) & 3) << 4);
    int grow = tid >> 2;
    const char* sA[4];
    const char* sB[2];
#pragma unroll
    for (int rr = 0; rr < 4; ++rr)
        sA[rr] = (const char*)A + (size_t)(m0 + grow + rr * 64) * K * 2 + scb;
#pragma unroll
    for (int rr = 0; rr < 2; ++rr)
        sB[rr] = (const char*)BT + (size_t)(n0 + grow + rr * 64) * K * 2 + scb;

    int inner = (lg * 16) ^ (((lr >> 1) & 3) << 4);
    int aoff = wrow * 8192 + lr * 64 + inner;           // A frag: +i*1024
    int boff = 16384 + wcol * 4096 + lr * 64 + inner;   // B frag: +j*1024

#define GSTAGE(OFS)                                                                                 \
    {                                                                                               \
        _Pragma("unroll")                                                                           \
        for (int rr = 0; rr < 4; ++rr) {                                                            \
            __builtin_amdgcn_global_load_lds((const AS1 void*)sA[rr],                               \
                (AS3 void*)(arena + (OFS) + tid * 16 + rr * 4096), 16, 0, 0);                       \
            sA[rr] += 64;                                                                           \
        }                                                                                           \
        _Pragma("unroll")                                                                           \
        for (int rr = 0; rr < 2; ++rr) {                                                            \
            __builtin_amdgcn_global_load_lds((const AS1 void*)sB[rr],                               \
                (AS3 void*)(arena + (OFS) + 16384 + tid * 16 + rr * 4096), 16, 0, 0);               \
            sB[rr] += 64;                                                                           \
        }                                                                                           \
    }

#define GCOMPUTE(OFS)                                                                               \
    {                                                                                               \
        short8 af[8], bf[4];                                                                        \
        _Pragma("unroll")                                                                           \
        for (int i = 0; i < 8; ++i)                                                                 \
            af[i] = *(const short8*)(arena + (OFS) + aoff + i * 1024);                              \
        _Pragma("unroll")                                                                           \
        for (int j = 0; j < 4; ++j)                                                                 \
            bf[j] = *(const short8*)(arena + (OFS) + boff + j * 1024);                              \
        __builtin_amdgcn_s_setprio(1);                                                              \
        _Pragma("unroll")                                                                           \
        for (int i = 0; i < 8; ++i)                                                                 \
            _Pragma("unroll")                                                                       \
            for (int j = 0; j < 4; ++j)                                                             \
                acc[i][j] = __builtin_amdgcn_mfma_f32_16x16x32_bf16(af[i], bf[j], acc[i][j], 0, 0, 0); \
        __builtin_amdgcn_s_setprio(0);                                                              \
    }

    int NT = K >> 5;
    int ofs0 = 0, ofs1 = 24576;

    GSTAGE(ofs0);
    asm volatile("s_waitcnt vmcnt(0)" ::: "memory");
    __builtin_amdgcn_s_barrier();
    __builtin_amdgcn_sched_barrier(0);

    for (int t = 0; t < NT; ++t) {
        if (t + 1 < NT) GSTAGE(ofs1);
        GCOMPUTE(ofs0);
        asm volatile("s_waitcnt vmcnt(0)" ::: "memory");
        __builtin_amdgcn_s_barrier();
        __builtin_amdgcn_sched_barrier(0);
        int tmp = ofs0; ofs0 = ofs1; ofs1 = tmp;
    }
#undef GSTAGE
#undef GCOMPUTE

#pragma unroll
    for (int i = 0; i < 8; ++i) {
        int row = m0 + wrow * 128 + i * 16 + lg * 4;
#pragma unroll
        for (int j = 0; j < 4; ++j) {
            int col = n0 + wcol * 64 + j * 16 + lr;
            float bv = bias[col];
#pragma unroll
            for (int r = 0; r < 4; ++r) {
                float v = acc[i][j][r] + bv;
                if (OUT_BF16) {
                    if (col < C_) v *= QK_SCALE;
                    outb[(size_t)(row + r) * N + col] = f2bf(v);
                } else {
                    outf[(size_t)(row + r) * N + col] = v;
                }
            }
        }
    }
}

// ---------------- GEMM (BM=128) for the proj GEMM ----------
__global__ __launch_bounds__(256, 3) void k_gemm_bt128(const unsigned short* __restrict__ A,
                                                       const unsigned short* __restrict__ BT,
                                                       const float* __restrict__ bias,
                                                       float* __restrict__ outf,
                                                       int M, int N, int K) {
    __shared__ __align__(16) char arena[49152];
    int tid = threadIdx.x;
    int w = tid >> 6, lane = tid & 63;
    int wrow = w >> 1, wcol = w & 1;

    int lin = blockIdx.y * gridDim.x + blockIdx.x;
    int nwg8 = (gridDim.x * gridDim.y) >> 3;
    int newlin = (lin & 7) * nwg8 + (lin >> 3);
    int bx = newlin % gridDim.x;
    int by = newlin / gridDim.x;
    int m0 = by * 128, n0 = bx * 128;

    int lr = lane & 15, lg = lane >> 4;

    f32x4 acc[4][4] = {};

    int scb = ((tid & 3) << 4) ^ (((tid >> 3) & 3) << 4);
    int grow = tid >> 2;
    const char* sA[2];
    const char* sB[2];
#pragma unroll
    for (int rr = 0; rr < 2; ++rr) {
        sA[rr] = (const char*)A + (size_t)(m0 + grow + rr * 64) * K * 2 + scb;
        sB[rr] = (const char*)BT + (size_t)(n0 + grow + rr * 64) * K * 2 + scb;
    }

    int inner = (lg * 16) ^ (((lr >> 1) & 3) << 4);
    int aoff = wrow * 4096 + lr * 64 + inner;
    int boff = 8192 + wcol * 4096 + lr * 64 + inner;

#define GSTAGE(OFS)                                                                                 \
    {                                                                                               \
        _Pragma("unroll")                                                                           \
        for (int rr = 0; rr < 2; ++rr) {                                                            \
            __builtin_amdgcn_global_load_lds((const AS1 void*)sA[rr],                               \
                (AS3 void*)(arena + (OFS) + tid * 16 + rr * 4096), 16, 0, 0);                       \
            sA[rr] += 64;                                                                           \
            __builtin_amdgcn_global_load_lds((const AS1 void*)sB[rr],                               \
                (AS3 void*)(arena + (OFS) + 8192 + tid * 16 + rr * 4096), 16, 0, 0);                \
            sB[rr] += 64;                                                                           \
        }                                                                                           \
    }

#define GCOMPUTE(OFS)                                                                               \
    {                                                                                               \
        short8 af[4], bf[4];                                                                        \
        _Pragma("unroll")                                                                           \
        for (int i = 0; i < 4; ++i)                                                                 \
            af[i] = *(const short8*)(arena + (OFS) + aoff + i * 1024);                              \
        _Pragma("unroll")                                                                           \
        for (int j = 0; j < 4; ++j)                                                                 \
            bf[j] = *(const short8*)(arena + (OFS) + boff + j * 1024);                              \
        __builtin_amdgcn_s_setprio(1);                                                              \
        _Pragma("unroll")                                                                           \
        for (int i = 0; i < 4; ++i)                                                                 \
            _Pragma("unroll")                                                                       \
            for (int j = 0; j < 4; ++j)                                                             \
                acc[i][j] = __builtin_amdgcn_mfma_f32_16x16x32_bf16(af[i], bf[j], acc[i][j], 0, 0, 0); \
        __builtin_amdgcn_s_setprio(0);                                                              \
    }

    int NT = K >> 5;
    int ofs0 = 0, ofs1 = 16384, ofs2 = 32768;

    GSTAGE(ofs0);
    GSTAGE(ofs1);
    asm volatile("s_waitcnt vmcnt(4)" ::: "memory");
    __builtin_amdgcn_s_barrier();
    __builtin_amdgcn_sched_barrier(0);

    for (int t = 0; t < NT; ++t) {
        bool pf = (t + 2 < NT);
        if (pf) GSTAGE(ofs2);
        GCOMPUTE(ofs0);
        if (pf) { asm volatile("s_waitcnt vmcnt(4)" ::: "memory"); }
        else    { asm volatile("s_waitcnt vmcnt(0)" ::: "memory"); }
        __builtin_amdgcn_s_barrier();
        __builtin_amdgcn_sched_barrier(0);
        int tmp = ofs0; ofs0 = ofs1; ofs1 = ofs2; ofs2 = tmp;
    }
#undef GSTAGE
#undef GCOMPUTE

#pragma unroll
    for (int i = 0; i < 4; ++i) {
        int row = m0 + wrow * 64 + i * 16 + lg * 4;
#pragma unroll
        for (int j = 0; j < 4; ++j) {
            int col = n0 + wcol * 64 + j * 16 + lr;
            float bv = bias[col];
#pragma unroll
            for (int r = 0; r < 4; ++r)
                outf[(size_t)(row + r) * N + col] = acc[i][j][r] + bv;
        }
    }
}

// ---------------- causal flash attention: QBLK=128, paired (512 blocks, uniform 34 tiles) ----
// LDS arena (48KB):
//   [0,16384)     K bufs 0/1 (8KB each)
//   [16384,32768) V bufs 0/1
//   [32768,49152) P per-wave (w*4096), per-qf +2048, half-parity swizzle
__global__ __launch_bounds__(256, 3) void k_attn(const unsigned short* __restrict__ qkv,
                                                 const unsigned short* __restrict__ vt,
                                                 unsigned short* __restrict__ y) {
    __shared__ __align__(16) char arena[49152];
    int tid = threadIdx.x;
    int w = tid >> 6, lane = tid & 63;
    int lr = lane & 15, lg = lane >> 4;

    // bijective XCD-chunk swizzle (512 % 8 == 0)
    int bid = blockIdx.x;
    int bid2 = (bid & 7) * 64 + (bid >> 3);
    int bh = bid2 >> 3, pair = bid2 & 7;
    int b = bh >> 4, h = bh & 15;

    const unsigned short* kbase = qkv + (size_t)(b * T_) * C3_ + C_ + h * D_;
    const unsigned short* vtb = vt + (size_t)bh * D_ * T_;

    int sw_ = (lr & 7) << 4;
    int RB0 = lr * 128 + ((lg * 16) ^ sw_);   // + LDSOFF; V: +16384
    int RB1 = RB0 ^ 64;

    int jl = (lr >> 1) & 3;
    int pbase = 32768 + w * 4096 + lr * 128
              + ((((lg >> 1) ^ (lr & 1)) << 4) | (((lg & 1) ^ (lr >> 3)) << 3));
    int pwa[4];
#pragma unroll
    for (int j = 0; j < 4; ++j) pwa[j] = pbase + ((j ^ jl) << 5);
    int prd0 = 32768 + w * 4096 + lr * 128 + ((lg ^ (lr & 7)) << 4);
    int prd1 = prd0 ^ 64;     // XOR not ADD: bit6 is inside the swizzled field
    int hs = lr & 8;
    int prA0a = prd0 + hs, prA0b = prd0 + (8 ^ hs);
    int prA1a = prd1 + hs, prA1b = prd1 + (8 ^ hs);

    int row0 = tid >> 3, row1 = 32 + (tid >> 3);
    int scol0 = ((tid & 7) << 4) ^ ((row0 & 7) << 4);
    int scol1 = ((tid & 7) << 4) ^ ((row1 & 7) << 4);

    const char *sK0, *sK1, *sV0, *sV1;

#define ASTAGE(LDSOFF)                                                                                  \
    {                                                                                                   \
        __builtin_amdgcn_global_load_lds((const AS1 void*)sK0, (AS3 void*)(arena + (LDSOFF) + w * 1024), 16, 0, 0);          \
        __builtin_amdgcn_global_load_lds((const AS1 void*)sK1, (AS3 void*)(arena + (LDSOFF) + 4096 + w * 1024), 16, 0, 0);   \
        __builtin_amdgcn_global_load_lds((const AS1 void*)sV0, (AS3 void*)(arena + 16384 + (LDSOFF) + w * 1024), 16, 0, 0);  \
        __builtin_amdgcn_global_load_lds((const AS1 void*)sV1, (AS3 void*)(arena + 16384 + (LDSOFF) + 4096 + w * 1024), 16, 0, 0); \
        sK0 += 64 * C3_ * 2; sK1 += 64 * C3_ * 2; sV0 += 128; sV1 += 128;                               \
    }

#define ACOMPUTE(LDSOFF, KT)                                                                            \
    {                                                                                                   \
        f32x4 s0[4], s1[4];                                                                             \
        __builtin_amdgcn_s_setprio(1);                                                                  \
        _Pragma("unroll")                                                                               \
        for (int j = 0; j < 4; ++j) {                                                                   \
            short8 kf0 = *(const short8*)(arena + RB0 + (LDSOFF) + j * 2048);                           \
            short8 kf1 = *(const short8*)(arena + RB1 + (LDSOFF) + j * 2048);                           \
            f32x4 z0 = {}, z1 = {};                                                                     \
            z0 = __builtin_amdgcn_mfma_f32_16x16x32_bf16(kf0, qA0, z0, 0, 0, 0);                        \
            s0[j] = __builtin_amdgcn_mfma_f32_16x16x32_bf16(kf1, qA1, z0, 0, 0, 0);                     \
            z1 = __builtin_amdgcn_mfma_f32_16x16x32_bf16(kf0, qB0, z1, 0, 0, 0);                        \
            s1[j] = __builtin_amdgcn_mfma_f32_16x16x32_bf16(kf1, qB1, z1, 0, 0, 0);                     \
        }                                                                                               \
        __builtin_amdgcn_s_setprio(0);                                                                  \
        if ((KT) >= ntiles - 2) {                                                                       \
            int kb0 = (KT) * 64 + lg * 4 - qv0;                                                         \
            _Pragma("unroll")                                                                           \
            for (int j = 0; j < 4; ++j)                                                                 \
                _Pragma("unroll")                                                                       \
                for (int r = 0; r < 4; ++r) {                                                           \
                    if (kb0 + j * 16 + r > 0)      s0[j][r] = -INFINITY;                                \
                    if (kb0 - 16 + j * 16 + r > 0) s1[j][r] = -INFINITY;  /* s1 rows at qv0+16 */       \
                }                                                                                       \
        }                                                                                               \
        _Pragma("unroll")                                                                               \
        for (int j = 0; j < 4; ++j)                                                                     \
            _Pragma("unroll")                                                                           \
            for (int r = 0; r < 4; ++r) {                                                               \
                float p0 = __builtin_amdgcn_exp2f(s0[j][r]);                                            \
                float p1 = __builtin_amdgcn_exp2f(s1[j][r]);                                            \
                s0[j][r] = p0; ls0 += p0;                                                               \
                s1[j][r] = p1; ls1 += p1;                                                               \
            }                                                                                           \
        _Pragma("unroll")                                                                               \
        for (int j = 0; j < 4; ++j) {                                                                   \
            uint2v W0, W1;                                                                              \
            W0[0] = pk_bf16(s0[j][0], s0[j][1]);                                                        \
            W0[1] = pk_bf16(s0[j][2], s0[j][3]);                                                        \
            W1[0] = pk_bf16(s1[j][0], s1[j][1]);                                                        \
            W1[1] = pk_bf16(s1[j][2], s1[j][3]);                                                        \
            *(uint2v*)(arena + pwa[j]) = W0;                                                            \
            *(uint2v*)(arena + pwa[j] + 2048) = W1;                                                     \
        }                                                                                               \
        short4v l00 = *(const short4v*)(arena + prA0a);                                                 \
        short4v h00 = *(const short4v*)(arena + prA0b);                                                 \
        short4v l01 = *(const short4v*)(arena + prA1a);                                                 \
        short4v h01 = *(const short4v*)(arena + prA1b);                                                 \
        short4v l10 = *(const short4v*)(arena + prA0a + 2048);                                          \
        short4v h10 = *(const short4v*)(arena + prA0b + 2048);                                          \
        short4v l11 = *(const short4v*)(arena + prA1a + 2048);                                          \
        short4v h11 = *(const short4v*)(arena + prA1b + 2048);                                          \
        short8 pa00 = __builtin_shufflevector(l00, h00, 0, 1, 2, 3, 4, 5, 6, 7);                        \
        short8 pa01 = __builtin_shufflevector(l01, h01, 0, 1, 2, 3, 4, 5, 6, 7);                        \
        short8 pa10 = __builtin_shufflevector(l10, h10, 0, 1, 2, 3, 4, 5, 6, 7);                        \
        short8 pa11 = __builtin_shufflevector(l11, h11, 0, 1, 2, 3, 4, 5, 6, 7);                        \
        __builtin_amdgcn_s_setprio(1);                                                                  \
        _Pragma("unroll")                                                                               \
        for (int dt = 0; dt < 4; ++dt) {                                                                \
            short8 vf0 = *(const short8*)(arena + RB0 + 16384 + (LDSOFF) + dt * 2048);                  \
            short8 vf1 = *(const short8*)(arena + RB1 + 16384 + (LDSOFF) + dt * 2048);                  \
            o0[dt] = __builtin_amdgcn_mfma_f32_16x16x32_bf16(pa00, vf0, o0[dt], 0, 0, 0);               \
            o0[dt] = __builtin_amdgcn_mfma_f32_16x16x32_bf16(pa01, vf1, o0[dt], 0, 0, 0);               \
            o1[dt] = __builtin_amdgcn_mfma_f32_16x16x32_bf16(pa10, vf0, o1[dt], 0, 0, 0);               \
            o1[dt] = __builtin_amdgcn_mfma_f32_16x16x32_bf16(pa11, vf1, o1[dt], 0, 0, 0);               \
        }                                                                                               \
        __builtin_amdgcn_s_setprio(0);                                                                  \
    }

#pragma unroll 1
    for (int half = 0; half < 2; ++half) {
        int qt = half ? (15 - pair) : pair;
        int q0 = qt * 128;
        int ntiles = 2 * qt + 2;

        const unsigned short* qrowA = qkv + (size_t)(b * T_ + q0 + w * 32 + lr) * C3_ + h * D_;
        const unsigned short* qrowB = qrowA + (size_t)16 * C3_;
        short8 qA0 = *(const short8*)(qrowA + lg * 8);
        short8 qA1 = *(const short8*)(qrowA + 32 + lg * 8);
        short8 qB0 = *(const short8*)(qrowB + lg * 8);
        short8 qB1 = *(const short8*)(qrowB + 32 + lg * 8);

        f32x4 o0[4] = {}, o1[4] = {};
        float ls0 = 0.f, ls1 = 0.f;
        int qv0 = q0 + w * 32 + lr;   // qf=0 row; qf=1 row = qv0+16

        sK0 = (const char*)(kbase + (size_t)row0 * C3_) + scol0;
        sK1 = (const char*)(kbase + (size_t)row1 * C3_) + scol1;
        sV0 = (const char*)(vtb + (size_t)row0 * T_) + scol0;
        sV1 = (const char*)(vtb + (size_t)row1 * T_) + scol1;

        ASTAGE(0);
        asm volatile("s_waitcnt vmcnt(0)" ::: "memory");
        __syncthreads();

#pragma unroll 1
        for (int kt = 0; kt < ntiles; kt += 2) {
            if (kt + 1 < ntiles) ASTAGE(8192);
            ACOMPUTE(0, kt);
            asm volatile("s_waitcnt vmcnt(0)" ::: "memory");
            __syncthreads();
            if (kt + 1 < ntiles) {
                if (kt + 2 < ntiles) ASTAGE(0);
                ACOMPUTE(8192, kt + 1);
                asm volatile("s_waitcnt vmcnt(0)" ::: "memory");
                __syncthreads();
            }
        }

        // ---- reduce ls over lg, normalize + store ----
        ls0 += __shfl_xor(ls0, 16); ls0 += __shfl_xor(ls0, 32);
        ls1 += __shfl_xor(ls1, 16); ls1 += __shfl_xor(ls1, 32);
#pragma unroll
        for (int r = 0; r < 4; ++r) {
            float l0 = __shfl(ls0, lg * 4 + r, 64);
            float l1 = __shfl(ls1, lg * 4 + r, 64);
            float i0 = 1.0f / l0, i1 = 1.0f / l1;
            int qa = q0 + w * 32 + lg * 4 + r;
            unsigned short* yrA = y + (size_t)(b * T_ + qa) * C_ + h * D_;
            unsigned short* yrB = yrA + (size_t)16 * C_;
#pragma unroll
            for (int dt = 0; dt < 4; ++dt) {
                yrA[dt * 16 + lr] = f2bf(o0[dt][r] * i0);
                yrB[dt * 16 + lr] = f2bf(o1[dt][r] * i1);
            }
        }
    }
#undef ASTAGE
#undef ACOMPUTE
}

extern "C" void kernel_launch(void* const* d_in, const int* in_sizes, int n_in,
                              void* d_out, int out_size, void* d_ws, size_t ws_size,
                              hipStream_t stream) {
    const float* x  = (const float*)d_in[0];
    const float* Wa = (const float*)d_in[1];
    const float* ba = (const float*)d_in[2];
    const float* Wp = (const float*)d_in[3];
    const float* bp = (const float*)d_in[4];
    float* out = (float*)d_out;

    char* ws = (char*)d_ws;
    unsigned short* xb  = (unsigned short*)(ws);                       // 16 MB
    unsigned short* wat = (unsigned short*)(ws + 16777216);            // 6 MB
    unsigned short* wpt = (unsigned short*)(ws + 23068672);            // 2 MB
    unsigned short* qkv = (unsigned short*)(ws + 25165824);            // 48 MB
    unsigned short* vt  = (unsigned short*)(ws + 75497472);            // 16 MB
    unsigned short* y   = xb;  // xb dead after GEMM1; reuse for attention output

    // fused prologue: x->bf16 + weight transposes (one dispatch)
    k_prep<<<12288, 256, 0, stream>>>(x, xb, Wa, wat, Wp, wpt);
    // qkv = x @ W_attn + b_attn   (bf16 out, Q pre-scaled; BM=256, 2-buffer, 3 blocks/CU)
    k_gemm_bt<true><<<dim3(C3_ / 128, (B_ * T_) / 256), 256, 0, stream>>>(
        xb, wat, ba, qkv, nullptr, B_ * T_, C3_, C_);
    // v -> vt[bh][d][t]
    k_prep_vt<<<dim3(T_ / 64, B_ * H_), 256, 0, stream>>>(qkv, vt);
    // attention (512 blocks: 8 pairs x 64 bh, uniform 34 tiles)
    k_attn<<<512, 256, 0, stream>>>(qkv, vt, y);
    // out = y @ W_proj + b_proj   (fp32 out, BM=128)
    k_gemm_bt128<<<dim3(C_ / 128, (B_ * T_) / 128), 256, 0, stream>>>(
        y, wpt, bp, out, B_ * T_, C_, C_);
}

// Round 20
// 155.531 us; speedup vs baseline: 1.6449x; 1.6449x over previous
//
#include <hip/hip_runtime.h>
#include <stdint.h>

typedef __attribute__((ext_vector_type(8))) short short8;
typedef __attribute__((ext_vector_type(4))) short short4v;
typedef __attribute__((ext_vector_type(4))) float f32x4;
typedef __attribute__((ext_vector_type(2))) unsigned int uint2v;

#define B_ 4
#define T_ 2048
#define C_ 1024
#define H_ 16
#define D_ 64
#define C3_ 3072

#define AS1 __attribute__((address_space(1)))
#define AS3 __attribute__((address_space(3)))

#define QK_SCALE 0.18033688f   /* 1/sqrt(64) * log2(e), folded into Q at GEMM1 epilogue */

__device__ __forceinline__ unsigned short f2bf(float f) {
    union { float f; uint32_t u; } v; v.f = f;
    uint32_t r = v.u + 0x7FFFu + ((v.u >> 16) & 1u);
    return (unsigned short)(r >> 16);
}

__device__ __forceinline__ uint32_t pk_bf16(float lo, float hi) {
    uint32_t r;
    asm("v_cvt_pk_bf16_f32 %0, %1, %2" : "=v"(r) : "v"(lo), "v"(hi));
    return r;
}

// ---------------- W[K][N] fp32 -> WT[N][K] bf16 (device helper) ----------------
__device__ __forceinline__ void wtrans_body(const float* __restrict__ W, unsigned short* __restrict__ WT,
                                            int K, int N, int n0, int k0, int tx, int ty,
                                            float (*t)[33]) {
#pragma unroll
    for (int i = 0; i < 4; ++i)
        t[ty + i * 8][tx] = W[(size_t)(k0 + ty + i * 8) * N + n0 + tx];
    __syncthreads();
#pragma unroll
    for (int i = 0; i < 4; ++i)
        WT[(size_t)(n0 + ty + i * 8) * K + k0 + tx] = f2bf(t[tx][ty + i * 8]);
}

// ---------------- fused prologue: x->bf16 + both weight transposes ----------------
// blocks [0,8192): cvt;  [8192,11264): Wa trans (96x32);  [11264,12288): Wp trans (32x32)
__global__ __launch_bounds__(256) void k_prep(const float* __restrict__ x, unsigned short* __restrict__ xb,
                                              const float* __restrict__ Wa, unsigned short* __restrict__ wat,
                                              const float* __restrict__ Wp, unsigned short* __restrict__ wpt) {
    __shared__ float t[32][33];
    int bid = blockIdx.x;
    int tid = threadIdx.x;
    if (bid < 8192) {
        int i = bid * 256 + tid;
        float4 v = ((const float4*)x)[i];
        unsigned short o0 = f2bf(v.x), o1 = f2bf(v.y), o2 = f2bf(v.z), o3 = f2bf(v.w);
        unsigned long long packed = (unsigned long long)o0 | ((unsigned long long)o1 << 16)
            | ((unsigned long long)o2 << 32) | ((unsigned long long)o3 << 48);
        *(unsigned long long*)(xb + (size_t)i * 4) = packed;
    } else if (bid < 11264) {
        int lb = bid - 8192;
        wtrans_body(Wa, wat, C_, C3_, (lb % 96) * 32, (lb / 96) * 32, tid & 31, tid >> 5, t);
    } else {
        int lb = bid - 11264;
        wtrans_body(Wp, wpt, C_, C_, (lb % 32) * 32, (lb / 32) * 32, tid & 31, tid >> 5, t);
    }
}

// ---------------- extract V head-major transposed: vt[bh][d][t] ----------------
__global__ void k_prep_vt(const unsigned short* __restrict__ qkv, unsigned short* __restrict__ vt) {
    int bh = blockIdx.y; int b = bh >> 4, h = bh & 15;
    int t0 = blockIdx.x * 64;
    __shared__ unsigned short tile[64][72];
    int tid = threadIdx.x;
    int r = tid >> 3;          // 0..31
    int c = (tid & 7) * 8;     // 0..56
#pragma unroll
    for (int rr = 0; rr < 64; rr += 32) {
        const unsigned short* src = qkv + (size_t)(b * T_ + t0 + r + rr) * C3_ + 2 * C_ + h * D_ + c;
        short8 v = *(const short8*)src;
#pragma unroll
        for (int j = 0; j < 8; ++j) tile[r + rr][c + j] = (unsigned short)v[j];
    }
    __syncthreads();
#pragma unroll
    for (int rr = 0; rr < 64; rr += 32) {
        int d = r + rr;
        short8 sv;
#pragma unroll
        for (int j = 0; j < 8; ++j) sv[j] = (short)tile[c + j][d];
        *(short8*)(vt + (size_t)bh * D_ * T_ + (size_t)d * T_ + t0 + c) = sv;
    }
}

// ---------------- GEMM (BM=256): C[M][N] = A @ BT^T + bias ----------------
// 3-buffer pipeline (24KB/buf = 72KB, 2 blocks/CU), counted vmcnt(6), raw s_barrier.
// NOTE: (256,2) is required — 3 blocks/CU would cap VGPRs below acc[8][4] and spill (r19).
template<bool OUT_BF16>
__global__ __launch_bounds__(256, 2) void k_gemm_bt(const unsigned short* __restrict__ A,
                                                    const unsigned short* __restrict__ BT,
                                                    const float* __restrict__ bias,
                                                    unsigned short* __restrict__ outb,
                                                    float* __restrict__ outf,
                                                    int M, int N, int K) {
    __shared__ __align__(16) char arena[73728];
    int tid = threadIdx.x;
    int w = tid >> 6, lane = tid & 63;
    int wrow = w >> 1, wcol = w & 1;

    int lin = blockIdx.y * gridDim.x + blockIdx.x;
    int nwg8 = (gridDim.x * gridDim.y) >> 3;
    int newlin = (lin & 7) * nwg8 + (lin >> 3);
    int bx = newlin % gridDim.x;
    int by = newlin / gridDim.x;
    int m0 = by * 256, n0 = bx * 128;

    int lr = lane & 15, lg = lane >> 4;

    f32x4 acc[8][4] = {};

    int scb = ((tid & 3) << 4) ^ (((tid >> 3) & 3) << 4);
    int grow = tid >> 2;
    const char* sA[4];
    const char* sB[2];
#pragma unroll
    for (int rr = 0; rr < 4; ++rr)
        sA[rr] = (const char*)A + (size_t)(m0 + grow + rr * 64) * K * 2 + scb;
#pragma unroll
    for (int rr = 0; rr < 2; ++rr)
        sB[rr] = (const char*)BT + (size_t)(n0 + grow + rr * 64) * K * 2 + scb;

    int inner = (lg * 16) ^ (((lr >> 1) & 3) << 4);
    int aoff = wrow * 8192 + lr * 64 + inner;           // A frag: +i*1024
    int boff = 16384 + wcol * 4096 + lr * 64 + inner;   // B frag: +j*1024

#define GSTAGE(OFS)                                                                                 \
    {                                                                                               \
        _Pragma("unroll")                                                                           \
        for (int rr = 0; rr < 4; ++rr) {                                                            \
            __builtin_amdgcn_global_load_lds((const AS1 void*)sA[rr],                               \
                (AS3 void*)(arena + (OFS) + tid * 16 + rr * 4096), 16, 0, 0);                       \
            sA[rr] += 64;                                                                           \
        }                                                                                           \
        _Pragma("unroll")                                                                           \
        for (int rr = 0; rr < 2; ++rr) {                                                            \
            __builtin_amdgcn_global_load_lds((const AS1 void*)sB[rr],                               \
                (AS3 void*)(arena + (OFS) + 16384 + tid * 16 + rr * 4096), 16, 0, 0);               \
            sB[rr] += 64;                                                                           \
        }                                                                                           \
    }

#define GCOMPUTE(OFS)                                                                               \
    {                                                                                               \
        short8 af[8], bf[4];                                                                        \
        _Pragma("unroll")                                                                           \
        for (int i = 0; i < 8; ++i)                                                                 \
            af[i] = *(const short8*)(arena + (OFS) + aoff + i * 1024);                              \
        _Pragma("unroll")                                                                           \
        for (int j = 0; j < 4; ++j)                                                                 \
            bf[j] = *(const short8*)(arena + (OFS) + boff + j * 1024);                              \
        __builtin_amdgcn_s_setprio(1);                                                              \
        _Pragma("unroll")                                                                           \
        for (int i = 0; i < 8; ++i)                                                                 \
            _Pragma("unroll")                                                                       \
            for (int j = 0; j < 4; ++j)                                                             \
                acc[i][j] = __builtin_amdgcn_mfma_f32_16x16x32_bf16(af[i], bf[j], acc[i][j], 0, 0, 0); \
        __builtin_amdgcn_s_setprio(0);                                                              \
    }

    int NT = K >> 5;
    int ofs0 = 0, ofs1 = 24576, ofs2 = 49152;

    GSTAGE(ofs0);
    GSTAGE(ofs1);
    asm volatile("s_waitcnt vmcnt(6)" ::: "memory");
    __builtin_amdgcn_s_barrier();
    __builtin_amdgcn_sched_barrier(0);

    for (int t = 0; t < NT; ++t) {
        bool pf = (t + 2 < NT);
        if (pf) GSTAGE(ofs2);
        GCOMPUTE(ofs0);
        if (pf) { asm volatile("s_waitcnt vmcnt(6)" ::: "memory"); }
        else    { asm volatile("s_waitcnt vmcnt(0)" ::: "memory"); }
        __builtin_amdgcn_s_barrier();
        __builtin_amdgcn_sched_barrier(0);
        int tmp = ofs0; ofs0 = ofs1; ofs1 = ofs2; ofs2 = tmp;
    }
#undef GSTAGE
#undef GCOMPUTE

#pragma unroll
    for (int i = 0; i < 8; ++i) {
        int row = m0 + wrow * 128 + i * 16 + lg * 4;
#pragma unroll
        for (int j = 0; j < 4; ++j) {
            int col = n0 + wcol * 64 + j * 16 + lr;
            float bv = bias[col];
#pragma unroll
            for (int r = 0; r < 4; ++r) {
                float v = acc[i][j][r] + bv;
                if (OUT_BF16) {
                    if (col < C_) v *= QK_SCALE;
                    outb[(size_t)(row + r) * N + col] = f2bf(v);
                } else {
                    outf[(size_t)(row + r) * N + col] = v;
                }
            }
        }
    }
}

// ---------------- GEMM (BM=128) for the proj GEMM ----------
__global__ __launch_bounds__(256, 3) void k_gemm_bt128(const unsigned short* __restrict__ A,
                                                       const unsigned short* __restrict__ BT,
                                                       const float* __restrict__ bias,
                                                       float* __restrict__ outf,
                                                       int M, int N, int K) {
    __shared__ __align__(16) char arena[49152];
    int tid = threadIdx.x;
    int w = tid >> 6, lane = tid & 63;
    int wrow = w >> 1, wcol = w & 1;

    int lin = blockIdx.y * gridDim.x + blockIdx.x;
    int nwg8 = (gridDim.x * gridDim.y) >> 3;
    int newlin = (lin & 7) * nwg8 + (lin >> 3);
    int bx = newlin % gridDim.x;
    int by = newlin / gridDim.x;
    int m0 = by * 128, n0 = bx * 128;

    int lr = lane & 15, lg = lane >> 4;

    f32x4 acc[4][4] = {};

    int scb = ((tid & 3) << 4) ^ (((tid >> 3) & 3) << 4);
    int grow = tid >> 2;
    const char* sA[2];
    const char* sB[2];
#pragma unroll
    for (int rr = 0; rr < 2; ++rr) {
        sA[rr] = (const char*)A + (size_t)(m0 + grow + rr * 64) * K * 2 + scb;
        sB[rr] = (const char*)BT + (size_t)(n0 + grow + rr * 64) * K * 2 + scb;
    }

    int inner = (lg * 16) ^ (((lr >> 1) & 3) << 4);
    int aoff = wrow * 4096 + lr * 64 + inner;
    int boff = 8192 + wcol * 4096 + lr * 64 + inner;

#define GSTAGE(OFS)                                                                                 \
    {                                                                                               \
        _Pragma("unroll")                                                                           \
        for (int rr = 0; rr < 2; ++rr) {                                                            \
            __builtin_amdgcn_global_load_lds((const AS1 void*)sA[rr],                               \
                (AS3 void*)(arena + (OFS) + tid * 16 + rr * 4096), 16, 0, 0);                       \
            sA[rr] += 64;                                                                           \
            __builtin_amdgcn_global_load_lds((const AS1 void*)sB[rr],                               \
                (AS3 void*)(arena + (OFS) + 8192 + tid * 16 + rr * 4096), 16, 0, 0);                \
            sB[rr] += 64;                                                                           \
        }                                                                                           \
    }

#define GCOMPUTE(OFS)                                                                               \
    {                                                                                               \
        short8 af[4], bf[4];                                                                        \
        _Pragma("unroll")                                                                           \
        for (int i = 0; i < 4; ++i)                                                                 \
            af[i] = *(const short8*)(arena + (OFS) + aoff + i * 1024);                              \
        _Pragma("unroll")                                                                           \
        for (int j = 0; j < 4; ++j)                                                                 \
            bf[j] = *(const short8*)(arena + (OFS) + boff + j * 1024);                              \
        __builtin_amdgcn_s_setprio(1);                                                              \
        _Pragma("unroll")                                                                           \
        for (int i = 0; i < 4; ++i)                                                                 \
            _Pragma("unroll")                                                                       \
            for (int j = 0; j < 4; ++j)                                                             \
                acc[i][j] = __builtin_amdgcn_mfma_f32_16x16x32_bf16(af[i], bf[j], acc[i][j], 0, 0, 0); \
        __builtin_amdgcn_s_setprio(0);                                                              \
    }

    int NT = K >> 5;
    int ofs0 = 0, ofs1 = 16384, ofs2 = 32768;

    GSTAGE(ofs0);
    GSTAGE(ofs1);
    asm volatile("s_waitcnt vmcnt(4)" ::: "memory");
    __builtin_amdgcn_s_barrier();
    __builtin_amdgcn_sched_barrier(0);

    for (int t = 0; t < NT; ++t) {
        bool pf = (t + 2 < NT);
        if (pf) GSTAGE(ofs2);
        GCOMPUTE(ofs0);
        if (pf) { asm volatile("s_waitcnt vmcnt(4)" ::: "memory"); }
        else    { asm volatile("s_waitcnt vmcnt(0)" ::: "memory"); }
        __builtin_amdgcn_s_barrier();
        __builtin_amdgcn_sched_barrier(0);
        int tmp = ofs0; ofs0 = ofs1; ofs1 = ofs2; ofs2 = tmp;
    }
#undef GSTAGE
#undef GCOMPUTE

#pragma unroll
    for (int i = 0; i < 4; ++i) {
        int row = m0 + wrow * 64 + i * 16 + lg * 4;
#pragma unroll
        for (int j = 0; j < 4; ++j) {
            int col = n0 + wcol * 64 + j * 16 + lr;
            float bv = bias[col];
#pragma unroll
            for (int r = 0; r < 4; ++r)
                outf[(size_t)(row + r) * N + col] = acc[i][j][r] + bv;
        }
    }
}

// ---------------- causal flash attention: QBLK=128, paired (512 blocks, uniform 34 tiles) ----
// LDS arena (48KB):
//   [0,16384)     K bufs 0/1 (8KB each)
//   [16384,32768) V bufs 0/1
//   [32768,49152) P per-wave (w*4096), per-qf +2048, half-parity swizzle
__global__ __launch_bounds__(256, 3) void k_attn(const unsigned short* __restrict__ qkv,
                                                 const unsigned short* __restrict__ vt,
                                                 unsigned short* __restrict__ y) {
    __shared__ __align__(16) char arena[49152];
    int tid = threadIdx.x;
    int w = tid >> 6, lane = tid & 63;
    int lr = lane & 15, lg = lane >> 4;

    // bijective XCD-chunk swizzle (512 % 8 == 0)
    int bid = blockIdx.x;
    int bid2 = (bid & 7) * 64 + (bid >> 3);
    int bh = bid2 >> 3, pair = bid2 & 7;
    int b = bh >> 4, h = bh & 15;

    const unsigned short* kbase = qkv + (size_t)(b * T_) * C3_ + C_ + h * D_;
    const unsigned short* vtb = vt + (size_t)bh * D_ * T_;

    int sw_ = (lr & 7) << 4;
    int RB0 = lr * 128 + ((lg * 16) ^ sw_);   // + LDSOFF; V: +16384
    int RB1 = RB0 ^ 64;

    int jl = (lr >> 1) & 3;
    int pbase = 32768 + w * 4096 + lr * 128
              + ((((lg >> 1) ^ (lr & 1)) << 4) | (((lg & 1) ^ (lr >> 3)) << 3));
    int pwa[4];
#pragma unroll
    for (int j = 0; j < 4; ++j) pwa[j] = pbase + ((j ^ jl) << 5);
    int prd0 = 32768 + w * 4096 + lr * 128 + ((lg ^ (lr & 7)) << 4);
    int prd1 = prd0 ^ 64;     // XOR not ADD: bit6 is inside the swizzled field
    int hs = lr & 8;
    int prA0a = prd0 + hs, prA0b = prd0 + (8 ^ hs);
    int prA1a = prd1 + hs, prA1b = prd1 + (8 ^ hs);

    int row0 = tid >> 3, row1 = 32 + (tid >> 3);
    int scol0 = ((tid & 7) << 4) ^ ((row0 & 7) << 4);
    int scol1 = ((tid & 7) << 4) ^ ((row1 & 7) << 4);

    const char *sK0, *sK1, *sV0, *sV1;

#define ASTAGE(LDSOFF)                                                                                  \
    {                                                                                                   \
        __builtin_amdgcn_global_load_lds((const AS1 void*)sK0, (AS3 void*)(arena + (LDSOFF) + w * 1024), 16, 0, 0);          \
        __builtin_amdgcn_global_load_lds((const AS1 void*)sK1, (AS3 void*)(arena + (LDSOFF) + 4096 + w * 1024), 16, 0, 0);   \
        __builtin_amdgcn_global_load_lds((const AS1 void*)sV0, (AS3 void*)(arena + 16384 + (LDSOFF) + w * 1024), 16, 0, 0);  \
        __builtin_amdgcn_global_load_lds((const AS1 void*)sV1, (AS3 void*)(arena + 16384 + (LDSOFF) + 4096 + w * 1024), 16, 0, 0); \
        sK0 += 64 * C3_ * 2; sK1 += 64 * C3_ * 2; sV0 += 128; sV1 += 128;                               \
    }

#define ACOMPUTE(LDSOFF, KT)                                                                            \
    {                                                                                                   \
        f32x4 s0[4], s1[4];                                                                             \
        __builtin_amdgcn_s_setprio(1);                                                                  \
        _Pragma("unroll")                                                                               \
        for (int j = 0; j < 4; ++j) {                                                                   \
            short8 kf0 = *(const short8*)(arena + RB0 + (LDSOFF) + j * 2048);                           \
            short8 kf1 = *(const short8*)(arena + RB1 + (LDSOFF) + j * 2048);                           \
            f32x4 z0 = {}, z1 = {};                                                                     \
            z0 = __builtin_amdgcn_mfma_f32_16x16x32_bf16(kf0, qA0, z0, 0, 0, 0);                        \
            s0[j] = __builtin_amdgcn_mfma_f32_16x16x32_bf16(kf1, qA1, z0, 0, 0, 0);                     \
            z1 = __builtin_amdgcn_mfma_f32_16x16x32_bf16(kf0, qB0, z1, 0, 0, 0);                        \
            s1[j] = __builtin_amdgcn_mfma_f32_16x16x32_bf16(kf1, qB1, z1, 0, 0, 0);                     \
        }                                                                                               \
        __builtin_amdgcn_s_setprio(0);                                                                  \
        if ((KT) >= ntiles - 2) {                                                                       \
            int kb0 = (KT) * 64 + lg * 4 - qv0;                                                         \
            _Pragma("unroll")                                                                           \
            for (int j = 0; j < 4; ++j)                                                                 \
                _Pragma("unroll")                                                                       \
                for (int r = 0; r < 4; ++r) {                                                           \
                    if (kb0 + j * 16 + r > 0)      s0[j][r] = -INFINITY;                                \
                    if (kb0 - 16 + j * 16 + r > 0) s1[j][r] = -INFINITY;  /* s1 rows at qv0+16 */       \
                }                                                                                       \
        }                                                                                               \
        _Pragma("unroll")                                                                               \
        for (int j = 0; j < 4; ++j)                                                                     \
            _Pragma("unroll")                                                                           \
            for (int r = 0; r < 4; ++r) {                                                               \
                float p0 = __builtin_amdgcn_exp2f(s0[j][r]);                                            \
                float p1 = __builtin_amdgcn_exp2f(s1[j][r]);                                            \
                s0[j][r] = p0; ls0 += p0;                                                               \
                s1[j][r] = p1; ls1 += p1;                                                               \
            }                                                                                           \
        _Pragma("unroll")                                                                               \
        for (int j = 0; j < 4; ++j) {                                                                   \
            uint2v W0, W1;                                                                              \
            W0[0] = pk_bf16(s0[j][0], s0[j][1]);                                                        \
            W0[1] = pk_bf16(s0[j][2], s0[j][3]);                                                        \
            W1[0] = pk_bf16(s1[j][0], s1[j][1]);                                                        \
            W1[1] = pk_bf16(s1[j][2], s1[j][3]);                                                        \
            *(uint2v*)(arena + pwa[j]) = W0;                                                            \
            *(uint2v*)(arena + pwa[j] + 2048) = W1;                                                     \
        }                                                                                               \
        short4v l00 = *(const short4v*)(arena + prA0a);                                                 \
        short4v h00 = *(const short4v*)(arena + prA0b);                                                 \
        short4v l01 = *(const short4v*)(arena + prA1a);                                                 \
        short4v h01 = *(const short4v*)(arena + prA1b);                                                 \
        short4v l10 = *(const short4v*)(arena + prA0a + 2048);                                          \
        short4v h10 = *(const short4v*)(arena + prA0b + 2048);                                          \
        short4v l11 = *(const short4v*)(arena + prA1a + 2048);                                          \
        short4v h11 = *(const short4v*)(arena + prA1b + 2048);                                          \
        short8 pa00 = __builtin_shufflevector(l00, h00, 0, 1, 2, 3, 4, 5, 6, 7);                        \
        short8 pa01 = __builtin_shufflevector(l01, h01, 0, 1, 2, 3, 4, 5, 6, 7);                        \
        short8 pa10 = __builtin_shufflevector(l10, h10, 0, 1, 2, 3, 4, 5, 6, 7);                        \
        short8 pa11 = __builtin_shufflevector(l11, h11, 0, 1, 2, 3, 4, 5, 6, 7);                        \
        __builtin_amdgcn_s_setprio(1);                                                                  \
        _Pragma("unroll")                                                                               \
        for (int dt = 0; dt < 4; ++dt) {                                                                \
            short8 vf0 = *(const short8*)(arena + RB0 + 16384 + (LDSOFF) + dt * 2048);                  \
            short8 vf1 = *(const short8*)(arena + RB1 + 16384 + (LDSOFF) + dt * 2048);                  \
            o0[dt] = __builtin_amdgcn_mfma_f32_16x16x32_bf16(pa00, vf0, o0[dt], 0, 0, 0);               \
            o0[dt] = __builtin_amdgcn_mfma_f32_16x16x32_bf16(pa01, vf1, o0[dt], 0, 0, 0);               \
            o1[dt] = __builtin_amdgcn_mfma_f32_16x16x32_bf16(pa10, vf0, o1[dt], 0, 0, 0);               \
            o1[dt] = __builtin_amdgcn_mfma_f32_16x16x32_bf16(pa11, vf1, o1[dt], 0, 0, 0);               \
        }                                                                                               \
        __builtin_amdgcn_s_setprio(0);                                                                  \
    }

#pragma unroll 1
    for (int half = 0; half < 2; ++half) {
        int qt = half ? (15 - pair) : pair;
        int q0 = qt * 128;
        int ntiles = 2 * qt + 2;

        const unsigned short* qrowA = qkv + (size_t)(b * T_ + q0 + w * 32 + lr) * C3_ + h * D_;
        const unsigned short* qrowB = qrowA + (size_t)16 * C3_;
        short8 qA0 = *(const short8*)(qrowA + lg * 8);
        short8 qA1 = *(const short8*)(qrowA + 32 + lg * 8);
        short8 qB0 = *(const short8*)(qrowB + lg * 8);
        short8 qB1 = *(const short8*)(qrowB + 32 + lg * 8);

        f32x4 o0[4] = {}, o1[4] = {};
        float ls0 = 0.f, ls1 = 0.f;
        int qv0 = q0 + w * 32 + lr;   // qf=0 row; qf=1 row = qv0+16

        sK0 = (const char*)(kbase + (size_t)row0 * C3_) + scol0;
        sK1 = (const char*)(kbase + (size_t)row1 * C3_) + scol1;
        sV0 = (const char*)(vtb + (size_t)row0 * T_) + scol0;
        sV1 = (const char*)(vtb + (size_t)row1 * T_) + scol1;

        ASTAGE(0);
        asm volatile("s_waitcnt vmcnt(0)" ::: "memory");
        __syncthreads();

#pragma unroll 1
        for (int kt = 0; kt < ntiles; kt += 2) {
            if (kt + 1 < ntiles) ASTAGE(8192);
            ACOMPUTE(0, kt);
            asm volatile("s_waitcnt vmcnt(0)" ::: "memory");
            __syncthreads();
            if (kt + 1 < ntiles) {
                if (kt + 2 < ntiles) ASTAGE(0);
                ACOMPUTE(8192, kt + 1);
                asm volatile("s_waitcnt vmcnt(0)" ::: "memory");
                __syncthreads();
            }
        }

        // ---- reduce ls over lg, normalize + store ----
        ls0 += __shfl_xor(ls0, 16); ls0 += __shfl_xor(ls0, 32);
        ls1 += __shfl_xor(ls1, 16); ls1 += __shfl_xor(ls1, 32);
#pragma unroll
        for (int r = 0; r < 4; ++r) {
            float l0 = __shfl(ls0, lg * 4 + r, 64);
            float l1 = __shfl(ls1, lg * 4 + r, 64);
            float i0 = 1.0f / l0, i1 = 1.0f / l1;
            int qa = q0 + w * 32 + lg * 4 + r;
            unsigned short* yrA = y + (size_t)(b * T_ + qa) * C_ + h * D_;
            unsigned short* yrB = yrA + (size_t)16 * C_;
#pragma unroll
            for (int dt = 0; dt < 4; ++dt) {
                yrA[dt * 16 + lr] = f2bf(o0[dt][r] * i0);
                yrB[dt * 16 + lr] = f2bf(o1[dt][r] * i1);
            }
        }
    }
#undef ASTAGE
#undef ACOMPUTE
}

extern "C" void kernel_launch(void* const* d_in, const int* in_sizes, int n_in,
                              void* d_out, int out_size, void* d_ws, size_t ws_size,
                              hipStream_t stream) {
    const float* x  = (const float*)d_in[0];
    const float* Wa = (const float*)d_in[1];
    const float* ba = (const float*)d_in[2];
    const float* Wp = (const float*)d_in[3];
    const float* bp = (const float*)d_in[4];
    float* out = (float*)d_out;

    char* ws = (char*)d_ws;
    unsigned short* xb  = (unsigned short*)(ws);                       // 16 MB
    unsigned short* wat = (unsigned short*)(ws + 16777216);            // 6 MB
    unsigned short* wpt = (unsigned short*)(ws + 23068672);            // 2 MB
    unsigned short* qkv = (unsigned short*)(ws + 25165824);            // 48 MB
    unsigned short* vt  = (unsigned short*)(ws + 75497472);            // 16 MB
    unsigned short* y   = xb;  // xb dead after GEMM1; reuse for attention output

    // fused prologue: x->bf16 + weight transposes (one dispatch)
    k_prep<<<12288, 256, 0, stream>>>(x, xb, Wa, wat, Wp, wpt);
    // qkv = x @ W_attn + b_attn   (bf16 out, Q pre-scaled; BM=256, 3-buffer, 2 blocks/CU)
    k_gemm_bt<true><<<dim3(C3_ / 128, (B_ * T_) / 256), 256, 0, stream>>>(
        xb, wat, ba, qkv, nullptr, B_ * T_, C3_, C_);
    // v -> vt[bh][d][t]
    k_prep_vt<<<dim3(T_ / 64, B_ * H_), 256, 0, stream>>>(qkv, vt);
    // attention (512 blocks: 8 pairs x 64 bh, uniform 34 tiles)
    k_attn<<<512, 256, 0, stream>>>(qkv, vt, y);
    // out = y @ W_proj + b_proj   (fp32 out, BM=128)
    k_gemm_bt128<<<dim3(C_ / 128, (B_ * T_) / 128), 256, 0, stream>>>(
        y, wpt, bp, out, B_ * T_, C_, C_);
}

// Round 21
// 151.550 us; speedup vs baseline: 1.6882x; 1.0263x over previous
//
#include <hip/hip_runtime.h>
#include <stdint.h>

typedef __attribute__((ext_vector_type(8))) short short8;
typedef __attribute__((ext_vector_type(4))) short short4v;
typedef __attribute__((ext_vector_type(4))) float f32x4;
typedef __attribute__((ext_vector_type(2))) unsigned int uint2v;

#define B_ 4
#define T_ 2048
#define C_ 1024
#define H_ 16
#define D_ 64
#define C3_ 3072

#define AS1 __attribute__((address_space(1)))
#define AS3 __attribute__((address_space(3)))

#define QK_SCALE 0.18033688f   /* 1/sqrt(64) * log2(e), folded into Q at GEMM1 epilogue */

__device__ __forceinline__ unsigned short f2bf(float f) {
    union { float f; uint32_t u; } v; v.f = f;
    uint32_t r = v.u + 0x7FFFu + ((v.u >> 16) & 1u);
    return (unsigned short)(r >> 16);
}

__device__ __forceinline__ uint32_t pk_bf16(float lo, float hi) {
    uint32_t r;
    asm("v_cvt_pk_bf16_f32 %0, %1, %2" : "=v"(r) : "v"(lo), "v"(hi));
    return r;
}

// ---------------- W[K][N] fp32 -> WT[N][K] bf16 (device helper) ----------------
__device__ __forceinline__ void wtrans_body(const float* __restrict__ W, unsigned short* __restrict__ WT,
                                            int K, int N, int n0, int k0, int tx, int ty,
                                            float (*t)[33]) {
#pragma unroll
    for (int i = 0; i < 4; ++i)
        t[ty + i * 8][tx] = W[(size_t)(k0 + ty + i * 8) * N + n0 + tx];
    __syncthreads();
#pragma unroll
    for (int i = 0; i < 4; ++i)
        WT[(size_t)(n0 + ty + i * 8) * K + k0 + tx] = f2bf(t[tx][ty + i * 8]);
}

// ---------------- fused prologue: x->bf16 + both weight transposes ----------------
// blocks [0,8192): cvt;  [8192,11264): Wa trans (96x32);  [11264,12288): Wp trans (32x32)
__global__ __launch_bounds__(256) void k_prep(const float* __restrict__ x, unsigned short* __restrict__ xb,
                                              const float* __restrict__ Wa, unsigned short* __restrict__ wat,
                                              const float* __restrict__ Wp, unsigned short* __restrict__ wpt) {
    __shared__ float t[32][33];
    int bid = blockIdx.x;
    int tid = threadIdx.x;
    if (bid < 8192) {
        int i = bid * 256 + tid;
        float4 v = ((const float4*)x)[i];
        unsigned short o0 = f2bf(v.x), o1 = f2bf(v.y), o2 = f2bf(v.z), o3 = f2bf(v.w);
        unsigned long long packed = (unsigned long long)o0 | ((unsigned long long)o1 << 16)
            | ((unsigned long long)o2 << 32) | ((unsigned long long)o3 << 48);
        *(unsigned long long*)(xb + (size_t)i * 4) = packed;
    } else if (bid < 11264) {
        int lb = bid - 8192;
        wtrans_body(Wa, wat, C_, C3_, (lb % 96) * 32, (lb / 96) * 32, tid & 31, tid >> 5, t);
    } else {
        int lb = bid - 11264;
        wtrans_body(Wp, wpt, C_, C_, (lb % 32) * 32, (lb / 32) * 32, tid & 31, tid >> 5, t);
    }
}

// ---------------- extract V head-major transposed: vt[bh][d][t] ----------------
__global__ void k_prep_vt(const unsigned short* __restrict__ qkv, unsigned short* __restrict__ vt) {
    int bh = blockIdx.y; int b = bh >> 4, h = bh & 15;
    int t0 = blockIdx.x * 64;
    __shared__ unsigned short tile[64][72];
    int tid = threadIdx.x;
    int r = tid >> 3;          // 0..31
    int c = (tid & 7) * 8;     // 0..56
#pragma unroll
    for (int rr = 0; rr < 64; rr += 32) {
        const unsigned short* src = qkv + (size_t)(b * T_ + t0 + r + rr) * C3_ + 2 * C_ + h * D_ + c;
        short8 v = *(const short8*)src;
#pragma unroll
        for (int j = 0; j < 8; ++j) tile[r + rr][c + j] = (unsigned short)v[j];
    }
    __syncthreads();
#pragma unroll
    for (int rr = 0; rr < 64; rr += 32) {
        int d = r + rr;
        short8 sv;
#pragma unroll
        for (int j = 0; j < 8; ++j) sv[j] = (short)tile[c + j][d];
        *(short8*)(vt + (size_t)bh * D_ * T_ + (size_t)d * T_ + t0 + c) = sv;
    }
}

// ---------------- GEMM (BM=256): C[M][N] = A @ BT^T + bias ----------------
// 3-buffer pipeline (24KB/buf = 72KB, 2 blocks/CU), counted vmcnt(6), raw s_barrier.
// NOTE: (256,2) is required — 3 blocks/CU would cap VGPRs below acc[8][4] and spill (r19).
template<bool OUT_BF16>
__global__ __launch_bounds__(256, 2) void k_gemm_bt(const unsigned short* __restrict__ A,
                                                    const unsigned short* __restrict__ BT,
                                                    const float* __restrict__ bias,
                                                    unsigned short* __restrict__ outb,
                                                    float* __restrict__ outf,
                                                    int M, int N, int K) {
    __shared__ __align__(16) char arena[73728];
    int tid = threadIdx.x;
    int w = tid >> 6, lane = tid & 63;
    int wrow = w >> 1, wcol = w & 1;

    int lin = blockIdx.y * gridDim.x + blockIdx.x;
    int nwg8 = (gridDim.x * gridDim.y) >> 3;
    int newlin = (lin & 7) * nwg8 + (lin >> 3);
    int bx = newlin % gridDim.x;
    int by = newlin / gridDim.x;
    int m0 = by * 256, n0 = bx * 128;

    int lr = lane & 15, lg = lane >> 4;

    f32x4 acc[8][4] = {};

    int scb = ((tid & 3) << 4) ^ (((tid >> 3) & 3) << 4);
    int grow = tid >> 2;
    const char* sA[4];
    const char* sB[2];
#pragma unroll
    for (int rr = 0; rr < 4; ++rr)
        sA[rr] = (const char*)A + (size_t)(m0 + grow + rr * 64) * K * 2 + scb;
#pragma unroll
    for (int rr = 0; rr < 2; ++rr)
        sB[rr] = (const char*)BT + (size_t)(n0 + grow + rr * 64) * K * 2 + scb;

    int inner = (lg * 16) ^ (((lr >> 1) & 3) << 4);
    int aoff = wrow * 8192 + lr * 64 + inner;           // A frag: +i*1024
    int boff = 16384 + wcol * 4096 + lr * 64 + inner;   // B frag: +j*1024

#define GSTAGE(OFS)                                                                                 \
    {                                                                                               \
        _Pragma("unroll")                                                                           \
        for (int rr = 0; rr < 4; ++rr) {                                                            \
            __builtin_amdgcn_global_load_lds((const AS1 void*)sA[rr],                               \
                (AS3 void*)(arena + (OFS) + tid * 16 + rr * 4096), 16, 0, 0);                       \
            sA[rr] += 64;                                                                           \
        }                                                                                           \
        _Pragma("unroll")                                                                           \
        for (int rr = 0; rr < 2; ++rr) {                                                            \
            __builtin_amdgcn_global_load_lds((const AS1 void*)sB[rr],                               \
                (AS3 void*)(arena + (OFS) + 16384 + tid * 16 + rr * 4096), 16, 0, 0);               \
            sB[rr] += 64;                                                                           \
        }                                                                                           \
    }

#define GCOMPUTE(OFS)                                                                               \
    {                                                                                               \
        short8 af[8], bf[4];                                                                        \
        _Pragma("unroll")                                                                           \
        for (int i = 0; i < 8; ++i)                                                                 \
            af[i] = *(const short8*)(arena + (OFS) + aoff + i * 1024);                              \
        _Pragma("unroll")                                                                           \
        for (int j = 0; j < 4; ++j)                                                                 \
            bf[j] = *(const short8*)(arena + (OFS) + boff + j * 1024);                              \
        __builtin_amdgcn_s_setprio(1);                                                              \
        _Pragma("unroll")                                                                           \
        for (int i = 0; i < 8; ++i)                                                                 \
            _Pragma("unroll")                                                                       \
            for (int j = 0; j < 4; ++j)                                                             \
                acc[i][j] = __builtin_amdgcn_mfma_f32_16x16x32_bf16(af[i], bf[j], acc[i][j], 0, 0, 0); \
        __builtin_amdgcn_s_setprio(0);                                                              \
    }

    int NT = K >> 5;
    int ofs0 = 0, ofs1 = 24576, ofs2 = 49152;

    GSTAGE(ofs0);
    GSTAGE(ofs1);
    asm volatile("s_waitcnt vmcnt(6)" ::: "memory");
    __builtin_amdgcn_s_barrier();
    __builtin_amdgcn_sched_barrier(0);

    for (int t = 0; t < NT; ++t) {
        bool pf = (t + 2 < NT);
        if (pf) GSTAGE(ofs2);
        GCOMPUTE(ofs0);
        if (pf) { asm volatile("s_waitcnt vmcnt(6)" ::: "memory"); }
        else    { asm volatile("s_waitcnt vmcnt(0)" ::: "memory"); }
        __builtin_amdgcn_s_barrier();
        __builtin_amdgcn_sched_barrier(0);
        int tmp = ofs0; ofs0 = ofs1; ofs1 = ofs2; ofs2 = tmp;
    }
#undef GSTAGE
#undef GCOMPUTE

#pragma unroll
    for (int i = 0; i < 8; ++i) {
        int row = m0 + wrow * 128 + i * 16 + lg * 4;
#pragma unroll
        for (int j = 0; j < 4; ++j) {
            int col = n0 + wcol * 64 + j * 16 + lr;
            float bv = bias[col];
#pragma unroll
            for (int r = 0; r < 4; ++r) {
                float v = acc[i][j][r] + bv;
                if (OUT_BF16) {
                    if (col < C_) v *= QK_SCALE;
                    outb[(size_t)(row + r) * N + col] = f2bf(v);
                } else {
                    outf[(size_t)(row + r) * N + col] = v;
                }
            }
        }
    }
}

// ---------------- GEMM (BM=128) for the proj GEMM ----------
__global__ __launch_bounds__(256, 3) void k_gemm_bt128(const unsigned short* __restrict__ A,
                                                       const unsigned short* __restrict__ BT,
                                                       const float* __restrict__ bias,
                                                       float* __restrict__ outf,
                                                       int M, int N, int K) {
    __shared__ __align__(16) char arena[49152];
    int tid = threadIdx.x;
    int w = tid >> 6, lane = tid & 63;
    int wrow = w >> 1, wcol = w & 1;

    int lin = blockIdx.y * gridDim.x + blockIdx.x;
    int nwg8 = (gridDim.x * gridDim.y) >> 3;
    int newlin = (lin & 7) * nwg8 + (lin >> 3);
    int bx = newlin % gridDim.x;
    int by = newlin / gridDim.x;
    int m0 = by * 128, n0 = bx * 128;

    int lr = lane & 15, lg = lane >> 4;

    f32x4 acc[4][4] = {};

    int scb = ((tid & 3) << 4) ^ (((tid >> 3) & 3) << 4);
    int grow = tid >> 2;
    const char* sA[2];
    const char* sB[2];
#pragma unroll
    for (int rr = 0; rr < 2; ++rr) {
        sA[rr] = (const char*)A + (size_t)(m0 + grow + rr * 64) * K * 2 + scb;
        sB[rr] = (const char*)BT + (size_t)(n0 + grow + rr * 64) * K * 2 + scb;
    }

    int inner = (lg * 16) ^ (((lr >> 1) & 3) << 4);
    int aoff = wrow * 4096 + lr * 64 + inner;
    int boff = 8192 + wcol * 4096 + lr * 64 + inner;

#define GSTAGE(OFS)                                                                                 \
    {                                                                                               \
        _Pragma("unroll")                                                                           \
        for (int rr = 0; rr < 2; ++rr) {                                                            \
            __builtin_amdgcn_global_load_lds((const AS1 void*)sA[rr],                               \
                (AS3 void*)(arena + (OFS) + tid * 16 + rr * 4096), 16, 0, 0);                       \
            sA[rr] += 64;                                                                           \
            __builtin_amdgcn_global_load_lds((const AS1 void*)sB[rr],                               \
                (AS3 void*)(arena + (OFS) + 8192 + tid * 16 + rr * 4096), 16, 0, 0);                \
            sB[rr] += 64;                                                                           \
        }                                                                                           \
    }

#define GCOMPUTE(OFS)                                                                               \
    {                                                                                               \
        short8 af[4], bf[4];                                                                        \
        _Pragma("unroll")                                                                           \
        for (int i = 0; i < 4; ++i)                                                                 \
            af[i] = *(const short8*)(arena + (OFS) + aoff + i * 1024);                              \
        _Pragma("unroll")                                                                           \
        for (int j = 0; j < 4; ++j)                                                                 \
            bf[j] = *(const short8*)(arena + (OFS) + boff + j * 1024);                              \
        __builtin_amdgcn_s_setprio(1);                                                              \
        _Pragma("unroll")                                                                           \
        for (int i = 0; i < 4; ++i)                                                                 \
            _Pragma("unroll")                                                                       \
            for (int j = 0; j < 4; ++j)                                                             \
                acc[i][j] = __builtin_amdgcn_mfma_f32_16x16x32_bf16(af[i], bf[j], acc[i][j], 0, 0, 0); \
        __builtin_amdgcn_s_setprio(0);                                                              \
    }

    int NT = K >> 5;
    int ofs0 = 0, ofs1 = 16384, ofs2 = 32768;

    GSTAGE(ofs0);
    GSTAGE(ofs1);
    asm volatile("s_waitcnt vmcnt(4)" ::: "memory");
    __builtin_amdgcn_s_barrier();
    __builtin_amdgcn_sched_barrier(0);

    for (int t = 0; t < NT; ++t) {
        bool pf = (t + 2 < NT);
        if (pf) GSTAGE(ofs2);
        GCOMPUTE(ofs0);
        if (pf) { asm volatile("s_waitcnt vmcnt(4)" ::: "memory"); }
        else    { asm volatile("s_waitcnt vmcnt(0)" ::: "memory"); }
        __builtin_amdgcn_s_barrier();
        __builtin_amdgcn_sched_barrier(0);
        int tmp = ofs0; ofs0 = ofs1; ofs1 = ofs2; ofs2 = tmp;
    }
#undef GSTAGE
#undef GCOMPUTE

#pragma unroll
    for (int i = 0; i < 4; ++i) {
        int row = m0 + wrow * 64 + i * 16 + lg * 4;
#pragma unroll
        for (int j = 0; j < 4; ++j) {
            int col = n0 + wcol * 64 + j * 16 + lr;
            float bv = bias[col];
#pragma unroll
            for (int r = 0; r < 4; ++r)
                outf[(size_t)(row + r) * N + col] = acc[i][j][r] + bv;
        }
    }
}

// ---------------- causal flash attention: QBLK=128, 8 waves x 16 q-rows (512 threads) ----------
// Re-partition of the r10-proven single-qf body: 512 blocks (paired, uniform 34 tiles),
// 2 blocks/CU x 8 waves = 16 waves/CU (4/SIMD) for latency hiding.
// LDS arena (48KB):
//   [0,16384)     K bufs 0/1 (8KB each)
//   [16384,32768) V bufs 0/1
//   [32768,49152) P per-wave (w*2048), conflict-free half-parity swizzle
__global__ __launch_bounds__(512, 4) void k_attn(const unsigned short* __restrict__ qkv,
                                                 const unsigned short* __restrict__ vt,
                                                 unsigned short* __restrict__ y) {
    __shared__ __align__(16) char arena[49152];
    int tid = threadIdx.x;
    int w = tid >> 6, lane = tid & 63;   // w in [0,8)
    int lr = lane & 15, lg = lane >> 4;

    // bijective XCD-chunk swizzle (512 % 8 == 0)
    int bid = blockIdx.x;
    int bid2 = (bid & 7) * 64 + (bid >> 3);
    int bh = bid2 >> 3, pair = bid2 & 7;
    int b = bh >> 4, h = bh & 15;

    const unsigned short* kbase = qkv + (size_t)(b * T_) * C3_ + C_ + h * D_;
    const unsigned short* vtb = vt + (size_t)bh * D_ * T_;

    // --- K/V frag addresses (tile-invariant; r10 formulas) ---
    int sw_ = (lr & 7) << 4;
    int RB0 = lr * 128 + ((lg * 16) ^ sw_);   // + LDSOFF; V: +16384
    int RB1 = RB0 ^ 64;

    // --- P addresses (r10 conflict-free half-parity swizzle, w in [0,8)) ---
    int jl = (lr >> 1) & 3;
    int pbase = 32768 + w * 2048 + lr * 128
              + ((((lg >> 1) ^ (lr & 1)) << 4) | (((lg & 1) ^ (lr >> 3)) << 3));
    int pwa[4];
#pragma unroll
    for (int j = 0; j < 4; ++j) pwa[j] = pbase + ((j ^ jl) << 5);
    int prd0 = 32768 + w * 2048 + lr * 128 + ((lg ^ (lr & 7)) << 4);
    int prd1 = prd0 ^ 64;     // XOR not ADD: bit6 is inside the swizzled field
    int hs = lr & 8;
    int prA0a = prd0 + hs, prA0b = prd0 + (8 ^ hs);
    int prA1a = prd1 + hs, prA1b = prd1 + (8 ^ hs);

    // --- global stage sources: 512 threads -> 1 K-load + 1 V-load each ---
    int grow = tid >> 3;                                   // 0..63
    int scol = ((tid & 7) << 4) ^ ((grow & 7) << 4);

    const char *sK, *sV;

#define ASTAGE(LDSOFF)                                                                                  \
    {                                                                                                   \
        __builtin_amdgcn_global_load_lds((const AS1 void*)sK, (AS3 void*)(arena + (LDSOFF) + tid * 16), 16, 0, 0);           \
        __builtin_amdgcn_global_load_lds((const AS1 void*)sV, (AS3 void*)(arena + 16384 + (LDSOFF) + tid * 16), 16, 0, 0);   \
        sK += 64 * C3_ * 2; sV += 128;                                                                  \
    }

#define ACOMPUTE(LDSOFF, KT)                                                                            \
    {                                                                                                   \
        f32x4 s[4];                                                                                     \
        __builtin_amdgcn_s_setprio(1);                                                                  \
        _Pragma("unroll")                                                                               \
        for (int j = 0; j < 4; ++j) {                                                                   \
            short8 kf0 = *(const short8*)(arena + RB0 + (LDSOFF) + j * 2048);                           \
            short8 kf1 = *(const short8*)(arena + RB1 + (LDSOFF) + j * 2048);                           \
            f32x4 z = {};                                                                               \
            z = __builtin_amdgcn_mfma_f32_16x16x32_bf16(kf0, qf0, z, 0, 0, 0);                          \
            s[j] = __builtin_amdgcn_mfma_f32_16x16x32_bf16(kf1, qf1, z, 0, 0, 0);                       \
        }                                                                                               \
        __builtin_amdgcn_s_setprio(0);                                                                  \
        if ((KT) >= ntiles - 2) {                                                                       \
            int kb = (KT) * 64 + lg * 4 - qv;                                                           \
            _Pragma("unroll")                                                                           \
            for (int j = 0; j < 4; ++j)                                                                 \
                _Pragma("unroll")                                                                       \
                for (int r = 0; r < 4; ++r)                                                             \
                    if (kb + j * 16 + r > 0) s[j][r] = -INFINITY;                                       \
        }                                                                                               \
        _Pragma("unroll")                                                                               \
        for (int j = 0; j < 4; ++j)                                                                     \
            _Pragma("unroll")                                                                           \
            for (int r = 0; r < 4; ++r) {                                                               \
                float pv = __builtin_amdgcn_exp2f(s[j][r]);                                             \
                s[j][r] = pv;                                                                           \
                ls += pv;                                                                               \
            }                                                                                           \
        _Pragma("unroll")                                                                               \
        for (int j = 0; j < 4; ++j) {                                                                   \
            uint2v W;                                                                                   \
            W[0] = pk_bf16(s[j][0], s[j][1]);                                                           \
            W[1] = pk_bf16(s[j][2], s[j][3]);                                                           \
            *(uint2v*)(arena + pwa[j]) = W;                                                             \
        }                                                                                               \
        short4v l0 = *(const short4v*)(arena + prA0a);                                                  \
        short4v h0 = *(const short4v*)(arena + prA0b);                                                  \
        short4v l1 = *(const short4v*)(arena + prA1a);                                                  \
        short4v h1 = *(const short4v*)(arena + prA1b);                                                  \
        short8 pa0 = __builtin_shufflevector(l0, h0, 0, 1, 2, 3, 4, 5, 6, 7);                           \
        short8 pa1 = __builtin_shufflevector(l1, h1, 0, 1, 2, 3, 4, 5, 6, 7);                           \
        __builtin_amdgcn_s_setprio(1);                                                                  \
        _Pragma("unroll")                                                                               \
        for (int dt = 0; dt < 4; ++dt) {                                                                \
            short8 vf0 = *(const short8*)(arena + RB0 + 16384 + (LDSOFF) + dt * 2048);                  \
            short8 vf1 = *(const short8*)(arena + RB1 + 16384 + (LDSOFF) + dt * 2048);                  \
            o[dt] = __builtin_amdgcn_mfma_f32_16x16x32_bf16(pa0, vf0, o[dt], 0, 0, 0);                  \
            o[dt] = __builtin_amdgcn_mfma_f32_16x16x32_bf16(pa1, vf1, o[dt], 0, 0, 0);                  \
        }                                                                                               \
        __builtin_amdgcn_s_setprio(0);                                                                  \
    }

#pragma unroll 1
    for (int half = 0; half < 2; ++half) {
        int qt = half ? (15 - pair) : pair;
        int q0 = qt * 128;
        int ntiles = 2 * qt + 2;

        const unsigned short* qrow = qkv + (size_t)(b * T_ + q0 + w * 16 + lr) * C3_ + h * D_;
        short8 qf0 = *(const short8*)(qrow + lg * 8);
        short8 qf1 = *(const short8*)(qrow + 32 + lg * 8);

        f32x4 o[4] = {};
        float ls = 0.f;    // in-lane partial of unnormalized row-sum (q = q0 + w*16 + lr)
        int qv = q0 + w * 16 + lr;

        sK = (const char*)(kbase + (size_t)grow * C3_) + scol;
        sV = (const char*)(vtb + (size_t)grow * T_) + scol;

        ASTAGE(0);
        asm volatile("s_waitcnt vmcnt(0)" ::: "memory");
        __syncthreads();

#pragma unroll 1
        for (int kt = 0; kt < ntiles; kt += 2) {
            if (kt + 1 < ntiles) ASTAGE(8192);
            ACOMPUTE(0, kt);
            asm volatile("s_waitcnt vmcnt(0)" ::: "memory");
            __syncthreads();
            if (kt + 1 < ntiles) {
                if (kt + 2 < ntiles) ASTAGE(0);
                ACOMPUTE(8192, kt + 1);
                asm volatile("s_waitcnt vmcnt(0)" ::: "memory");
                __syncthreads();
            }
        }

        // ---- combine lg-partials of ls, normalize + store ----
        ls += __shfl_xor(ls, 16);
        ls += __shfl_xor(ls, 32);
#pragma unroll
        for (int r = 0; r < 4; ++r) {
            float lst = __shfl(ls, lg * 4 + r, 64);
            float inv = 1.0f / lst;
            int q = q0 + w * 16 + lg * 4 + r;
            unsigned short* yrow = y + (size_t)(b * T_ + q) * C_ + h * D_;
#pragma unroll
            for (int dt = 0; dt < 4; ++dt)
                yrow[dt * 16 + lr] = f2bf(o[dt][r] * inv);
        }
    }
#undef ASTAGE
#undef ACOMPUTE
}

extern "C" void kernel_launch(void* const* d_in, const int* in_sizes, int n_in,
                              void* d_out, int out_size, void* d_ws, size_t ws_size,
                              hipStream_t stream) {
    const float* x  = (const float*)d_in[0];
    const float* Wa = (const float*)d_in[1];
    const float* ba = (const float*)d_in[2];
    const float* Wp = (const float*)d_in[3];
    const float* bp = (const float*)d_in[4];
    float* out = (float*)d_out;

    char* ws = (char*)d_ws;
    unsigned short* xb  = (unsigned short*)(ws);                       // 16 MB
    unsigned short* wat = (unsigned short*)(ws + 16777216);            // 6 MB
    unsigned short* wpt = (unsigned short*)(ws + 23068672);            // 2 MB
    unsigned short* qkv = (unsigned short*)(ws + 25165824);            // 48 MB
    unsigned short* vt  = (unsigned short*)(ws + 75497472);            // 16 MB
    unsigned short* y   = xb;  // xb dead after GEMM1; reuse for attention output

    // fused prologue: x->bf16 + weight transposes (one dispatch)
    k_prep<<<12288, 256, 0, stream>>>(x, xb, Wa, wat, Wp, wpt);
    // qkv = x @ W_attn + b_attn   (bf16 out, Q pre-scaled; BM=256, 3-buffer, 2 blocks/CU)
    k_gemm_bt<true><<<dim3(C3_ / 128, (B_ * T_) / 256), 256, 0, stream>>>(
        xb, wat, ba, qkv, nullptr, B_ * T_, C3_, C_);
    // v -> vt[bh][d][t]
    k_prep_vt<<<dim3(T_ / 64, B_ * H_), 256, 0, stream>>>(qkv, vt);
    // attention (512 blocks x 512 threads: 8 pairs x 64 bh, uniform 34 tiles, 16 waves/CU)
    k_attn<<<512, 512, 0, stream>>>(qkv, vt, y);
    // out = y @ W_proj + b_proj   (fp32 out, BM=128)
    k_gemm_bt128<<<dim3(C_ / 128, (B_ * T_) / 128), 256, 0, stream>>>(
        y, wpt, bp, out, B_ * T_, C_, C_);
}